// Round 7
// baseline (665.172 us; speedup 1.0000x reference)
//
#include <hip/hip_runtime.h>

#define B_SZ   4096
#define IN_SZ  1024
#define V_SZ   48
#define H_SZ   512
#define OUT_SZ 64

typedef __attribute__((ext_vector_type(4))) float f32x4;
typedef __attribute__((ext_vector_type(8))) short bf16x8;   // 8 bf16 in 4 VGPRs
typedef __attribute__((ext_vector_type(4))) short short4v;
typedef __attribute__((ext_vector_type(4))) float float4v;

// fp32 -> bf16 round-to-nearest-even
__device__ __forceinline__ short f2bf(float f){
    unsigned u = __builtin_bit_cast(unsigned, f);
    u += 0x7fffu + ((u >> 16) & 1u);
    return (short)(u >> 16);
}

// async global->LDS, 16B per lane; LDS dest is wave-uniform base + lane*16
__device__ __forceinline__ void gl2lds16(const void* g, void* l){
    __builtin_amdgcn_global_load_lds(
        (const __attribute__((address_space(1))) void*)g,
        (__attribute__((address_space(3))) void*)l, 16, 0, 0);
}

#define MFMA_B16(d, a, b) d = __builtin_amdgcn_mfma_f32_16x16x32_bf16(a, b, d, 0, 0, 0)

// ---------------- merged pre-pass: convert x + transpose-convert W1/W2/W3 ----
// one launch instead of four; per-block uniform branch on flat blockIdx.
#define PRE_CONV 4096                       // B_SZ*IN_SZ/1024
#define PRE_W1   6144                       // (H/64)*(IN/64)*V = 8*16*48
#define PRE_W2   3072                       // 8*8*48
#define PRE_W3   384                        // 1*8*48
#define PRE_NBLK (PRE_CONV + PRE_W1 + PRE_W2 + PRE_W3)

__device__ __forceinline__ void transpose_cvt_body(
    const float* __restrict__ in, short* __restrict__ out, int R, int C,
    int bx, int by, int v, int tid, short (*t)[68])
{
    int c0 = bx * 64, r0 = by * 64;
    size_t base = (size_t)v * R * C;
    const float* inp = in + base + (size_t)r0 * C + c0;
    int g    = tid >> 4;                             // 0..15
    int col4 = (tid & 15) * 4;
    #pragma unroll
    for (int p = 0; p < 4; ++p){
        int row = p*16 + g;
        float4v f = *(const float4v*)&inp[(size_t)row * C + col4];
        short4v s = { f2bf(f.x), f2bf(f.y), f2bf(f.z), f2bf(f.w) };
        *(short4v*)&t[row][col4] = s;
    }
    __syncthreads();
    short* outp = out + base + (size_t)c0 * R + r0;
    int r4 = (tid & 15) * 4;
    #pragma unroll
    for (int p = 0; p < 4; ++p){
        int c = p*16 + g;
        short4v s = { t[r4+0][c], t[r4+1][c], t[r4+2][c], t[r4+3][c] };
        *(short4v*)&outp[(size_t)c * R + r4] = s;
    }
}

__global__ __launch_bounds__(256) void k_prepass(
    const float* __restrict__ x,  short* __restrict__ xb,
    const float* __restrict__ W1, short* __restrict__ W1t,
    const float* __restrict__ W2, short* __restrict__ W2t,
    const float* __restrict__ W3, short* __restrict__ W3t)
{
    __shared__ short t[64][68];                      // 68-short stride: 8B-aligned rows
    const int bid = blockIdx.x;
    const int tid = threadIdx.x;
    if (bid < PRE_CONV){
        int i = bid * 256 + tid;                     // one float4 per thread
        float4v f = ((const float4v*)x)[i];
        short4v o = { f2bf(f.x), f2bf(f.y), f2bf(f.z), f2bf(f.w) };
        ((short4v*)xb)[i] = o;
    } else if (bid < PRE_CONV + PRE_W1){
        int l = bid - PRE_CONV;                      // grid (8, 16, 48)
        transpose_cvt_body(W1, W1t, IN_SZ, H_SZ, l & 7, (l >> 3) & 15, l >> 7, tid, t);
    } else if (bid < PRE_CONV + PRE_W1 + PRE_W2){
        int l = bid - (PRE_CONV + PRE_W1);           // grid (8, 8, 48)
        transpose_cvt_body(W2, W2t, H_SZ, H_SZ, l & 7, (l >> 3) & 7, l >> 6, tid, t);
    } else {
        int l = bid - (PRE_CONV + PRE_W1 + PRE_W2);  // grid (1, 8, 48)
        transpose_cvt_body(W3, W3t, H_SZ, OUT_SZ, 0, l & 7, l >> 3, tid, t);
    }
}

// ---------------- layer 1: 256x256 8-phase GEMM + bias + relu + bf16 store ----
// Byte-identical to the round-1 kernel (passed correctness on HW) EXCEPT
// __launch_bounds__(512, 2): LDS=128KB forces 1 block/CU (2 waves/SIMD), so
// the default 128-VGPR cap bought nothing and spilled ~215 B/thread (R1:
// WRITE_SIZE 370 vs 201 MB ideal). (512,2) raises the cap to 256 -> no spill.
#define G1_TILE (256*64)
#define G1_NT   (IN_SZ/64)

__global__ __launch_bounds__(512, 2) void k_gemm1(
    const short* __restrict__ xb, const short* __restrict__ W1t,
    const float* __restrict__ b1, short* __restrict__ h1)
{
    __shared__ __align__(16) short As[2*G1_TILE];    // 64 KB
    __shared__ __align__(16) short Bs[2*G1_TILE];    // 64 KB
    const int tid  = threadIdx.x;
    const int lane = tid & 63, wave = tid >> 6;
    const int l15  = lane & 15, quad = lane >> 4;
    const int wm = wave >> 2, wn = wave & 3;         // 2M x 4N
    const int M0 = blockIdx.x * 256;
    const int N0 = blockIdx.y * 256;
    const int v  = blockIdx.z;

    const short* apan = xb  + (size_t)M0 * IN_SZ;
    const short* bpan = W1t + ((size_t)v * H_SZ + N0) * IN_SZ;

    const int lr    = tid >> 3;                          // 0..63
    const int toff  = lr * IN_SZ + (((tid & 7) ^ (lr & 7)) * 8);
    const int wbase = tid & ~63;

    auto stage = [&](const short* pan, short* lbase, int h, int j, int t){
        gl2lds16(pan + (size_t)(h*128 + j*64) * IN_SZ + t*64 + toff,
                 lbase + (h*1024 + j*512 + wbase) * 8);
    };
    auto stage_half = [&](const short* pan, short* lbase, int h, int t){
        stage(pan, lbase, h, 0, t);
        stage(pan, lbase, h, 1, t);
    };

    // prologue: tile0 (4 halves) + tile1 A-halves; allow tile1 A in flight
    stage_half(apan, As, 0, 0); stage_half(apan, As, 1, 0);
    stage_half(bpan, Bs, 0, 0); stage_half(bpan, Bs, 1, 0);
    stage_half(apan, As + G1_TILE, 0, 1); stage_half(apan, As + G1_TILE, 1, 1);
    asm volatile("s_waitcnt vmcnt(4)" ::: "memory");
    __builtin_amdgcn_s_barrier();

    f32x4 acc[8][4];
    #pragma unroll
    for (int i = 0; i < 8; ++i)
        #pragma unroll
        for (int j = 0; j < 4; ++j) acc[i][j] = (f32x4){0.f,0.f,0.f,0.f};

    // ds_read addressing: element (row,k): slot = row*8 + ((k>>3)^(row&7))
    const int x7 = l15 & 7;
    const int abase = (wm*128 + l15) * 64;   // short index of row base
    const int bbase = (wn*64  + l15) * 64;
    const int c_kk0 = ((quad)     ^ x7) * 8; // chunk offset, k-step 0
    const int c_kk1 = ((quad + 4) ^ x7) * 8; // chunk offset, k-step 1

    #pragma unroll 2
    for (int t = 0; t < G1_NT; ++t){
        short* Ac = As + (t & 1) * G1_TILE;          // current buffers
        short* Bc = Bs + (t & 1) * G1_TILE;
        short* Bn = Bs + ((t + 1) & 1) * G1_TILE;    // next-tile B target

        bf16x8 a0[8], a1[8];

        // ---- phase 1: read A@kk0 + B c0,c1@kk0; stage B(t+1,h0); MFMA c0,c1@kk0
        #pragma unroll
        for (int rf = 0; rf < 8; ++rf)
            a0[rf] = *(const bf16x8*)&Ac[abase + rf*1024 + c_kk0];
        bf16x8 b00 = *(const bf16x8*)&Bc[bbase + 0*1024 + c_kk0];
        bf16x8 b01 = *(const bf16x8*)&Bc[bbase + 1*1024 + c_kk0];
        if (t + 1 < G1_NT) stage_half(bpan, Bn, 0, t + 1);
        __builtin_amdgcn_s_barrier();
        asm volatile("s_waitcnt lgkmcnt(0)" ::: "memory");
        __builtin_amdgcn_s_setprio(1);
        #pragma unroll
        for (int rf = 0; rf < 8; ++rf){
            MFMA_B16(acc[rf][0], a0[rf], b00);
            MFMA_B16(acc[rf][1], a0[rf], b01);
        }
        __builtin_amdgcn_s_setprio(0);
        __builtin_amdgcn_s_barrier();

        // ---- phase 2: read A@kk1 + B c2,c3@kk0; stage B(t+1,h1); MFMA c2,c3@kk0
        #pragma unroll
        for (int rf = 0; rf < 8; ++rf)
            a1[rf] = *(const bf16x8*)&Ac[abase + rf*1024 + c_kk1];
        bf16x8 b02 = *(const bf16x8*)&Bc[bbase + 2*1024 + c_kk0];
        bf16x8 b03 = *(const bf16x8*)&Bc[bbase + 3*1024 + c_kk0];
        if (t + 1 < G1_NT) stage_half(bpan, Bn, 1, t + 1);
        __builtin_amdgcn_s_barrier();
        asm volatile("s_waitcnt lgkmcnt(0)" ::: "memory");
        __builtin_amdgcn_s_setprio(1);
        #pragma unroll
        for (int rf = 0; rf < 8; ++rf){
            MFMA_B16(acc[rf][2], a0[rf], b02);
            MFMA_B16(acc[rf][3], a0[rf], b03);
        }
        __builtin_amdgcn_s_setprio(0);
        __builtin_amdgcn_s_barrier();

        // ---- phase 3: read B c0,c1@kk1; stage A(t+2,h0) into CURRENT buf
        bf16x8 b10 = *(const bf16x8*)&Bc[bbase + 0*1024 + c_kk1];
        bf16x8 b11 = *(const bf16x8*)&Bc[bbase + 1*1024 + c_kk1];
        if (t + 2 < G1_NT) stage_half(apan, Ac, 0, t + 2);
        __builtin_amdgcn_s_barrier();
        asm volatile("s_waitcnt lgkmcnt(0)" ::: "memory");
        __builtin_amdgcn_s_setprio(1);
        #pragma unroll
        for (int rf = 0; rf < 8; ++rf){
            MFMA_B16(acc[rf][0], a1[rf], b10);
            MFMA_B16(acc[rf][1], a1[rf], b11);
        }
        __builtin_amdgcn_s_setprio(0);
        __builtin_amdgcn_s_barrier();

        // ---- phase 4: read B c2,c3@kk1; stage A(t+2,h1); MFMA; counted vmcnt
        bf16x8 b12 = *(const bf16x8*)&Bc[bbase + 2*1024 + c_kk1];
        bf16x8 b13 = *(const bf16x8*)&Bc[bbase + 3*1024 + c_kk1];
        if (t + 2 < G1_NT) stage_half(apan, Ac, 1, t + 2);
        __builtin_amdgcn_s_barrier();
        asm volatile("s_waitcnt lgkmcnt(0)" ::: "memory");
        __builtin_amdgcn_s_setprio(1);
        #pragma unroll
        for (int rf = 0; rf < 8; ++rf){
            MFMA_B16(acc[rf][2], a1[rf], b12);
            MFMA_B16(acc[rf][3], a1[rf], b13);
        }
        __builtin_amdgcn_s_setprio(0);
        // tile boundary: tile t+1 must be landed; allow t+2's A-halves in flight
        if (t + 2 < G1_NT)      { asm volatile("s_waitcnt vmcnt(4)" ::: "memory"); }
        else if (t + 1 < G1_NT) { asm volatile("s_waitcnt vmcnt(0)" ::: "memory"); }
        __builtin_amdgcn_s_barrier();
    }

    // epilogue: bias + relu + bf16 store
    const float* bv = b1 + (size_t)v * H_SZ;
    short* cv = h1 + (size_t)v * (B_SZ*H_SZ);
    #pragma unroll
    for (int cf = 0; cf < 4; ++cf){
        int col = N0 + wn*64 + cf*16 + l15;
        float bb = bv[col];
        #pragma unroll
        for (int rf = 0; rf < 8; ++rf){
            int rowb = M0 + wm*128 + rf*16 + quad*4;
            #pragma unroll
            for (int r = 0; r < 4; ++r){
                float val = acc[rf][cf][r] + bb;
                val = val > 0.f ? val : 0.f;
                cv[(size_t)(rowb + r) * H_SZ + col] = f2bf(val);
            }
        }
    }
}

// ---------------- layers 2+3 fused, full-N trick ----------------
// Phase 2: BM=64, BN=512(=H), BK=64, 512 thr = 8 waves of 64x64 (proven R0
// version). Epilogue: relu(h2) tile -> LDS (reuses Bs, 64KB). Phase 3 now
// uses ALL 8 waves (2M x 4N over the 64x64 out tile; proven correct in R5).
__global__ __launch_bounds__(512) void k_gemm23(
    const short* __restrict__ h, const short* __restrict__ W2t,
    const float* __restrict__ b2, const short* __restrict__ W3t,
    float* __restrict__ out)
{
    __shared__ __align__(16) short As[64*64];     // 8 KB
    __shared__ __align__(16) short Bs[512*64];    // 64 KB; aliased as h2s[64][512] later
    const int tid  = threadIdx.x;
    const int lane = tid & 63, wave = tid >> 6;   // wave = n-slot 0..7 in phase 2
    const int l15  = lane & 15, quad = lane >> 4;
    const int M0 = blockIdx.x * 64;
    const int v  = blockIdx.y;

    const short* hv  = h   + (size_t)v * (B_SZ*H_SZ) + (size_t)M0 * H_SZ;
    const short* w2v = W2t + (size_t)v * (H_SZ*H_SZ);
    const short* w3v = W3t + (size_t)v * (OUT_SZ*H_SZ);

    // staging: row = tid>>3 (+j*64 for B), chunk swizzle same for all j
    const int rowT = tid >> 3;
    const int wT   = (tid & 7) ^ (rowT & 7);
    const short* asrc  = hv  + (size_t)rowT * H_SZ + wT*8;
    const short* bsrc0 = w2v + (size_t)rowT * H_SZ + wT*8;
    short* adst  = &As[(size_t)(tid & ~63) * 8];
    short* bdst0 = &Bs[(size_t)(tid & ~63) * 8];

    f32x4 acc[4][4];
    #pragma unroll
    for (int i = 0; i < 4; ++i)
        #pragma unroll
        for (int j = 0; j < 4; ++j) acc[i][j] = (f32x4){0.f,0.f,0.f,0.f};

    for (int k0 = 0; k0 < H_SZ; k0 += 64){
        gl2lds16(asrc + k0, adst);
        #pragma unroll
        for (int j = 0; j < 8; ++j)
            gl2lds16(bsrc0 + (size_t)j*(64*H_SZ) + k0, bdst0 + (size_t)j*512*8);
        __syncthreads();
        #pragma unroll
        for (int kk = 0; kk < 2; ++kk){
            bf16x8 a[4], b[4];
            #pragma unroll
            for (int tm = 0; tm < 4; ++tm){
                int m = tm*16 + l15;
                int slot = m*8 + ((kk*4 + quad) ^ (m & 7));
                a[tm] = *(const bf16x8*)&As[slot*8];
            }
            #pragma unroll
            for (int tn = 0; tn < 4; ++tn){
                int n = wave*64 + tn*16 + l15;
                int slot = n*8 + ((kk*4 + quad) ^ (n & 7));
                b[tn] = *(const bf16x8*)&Bs[slot*8];
            }
            #pragma unroll
            for (int tm = 0; tm < 4; ++tm)
                #pragma unroll
                for (int tn = 0; tn < 4; ++tn)
                    acc[tm][tn] = __builtin_amdgcn_mfma_f32_16x16x32_bf16(
                        a[tm], b[tn], acc[tm][tn], 0, 0, 0);
        }
        __syncthreads();
    }

    // phase-2 epilogue: bias+relu+bf16 -> h2s in LDS (swizzled [64 rows][64 units])
    // element (row,k): Bs[row*512 + ((k>>3)^(row&7))*8 + (k&7)]
    const float* bv = b2 + (size_t)v * H_SZ;
    #pragma unroll
    for (int tn = 0; tn < 4; ++tn){
        int col = wave*64 + tn*16 + l15;
        float bb = bv[col];
        int u = col >> 3, c7 = col & 7;
        #pragma unroll
        for (int tm = 0; tm < 4; ++tm){
            int rowb = tm*16 + quad*4;
            #pragma unroll
            for (int r = 0; r < 4; ++r){
                int row = rowb + r;
                float val = acc[tm][tn][r] + bb;
                val = val > 0.f ? val : 0.f;
                Bs[row*512 + ((u ^ (row & 7))*8) + c7] = f2bf(val);
            }
        }
    }
    __syncthreads();

    // phase 3: out[M0+m][v*64+n] = h2[m][:] @ W3t[v][n][:]^T ; ALL 8 waves
    // (2M x 4N: wm3 = row half, wn3 = col group; proven correct in R5's run)
    {
        const int wm3 = wave >> 2;
        const int wn3 = wave & 3;
        f32x4 acc3[2];
        #pragma unroll
        for (int i = 0; i < 2; ++i) acc3[i] = (f32x4){0.f,0.f,0.f,0.f};
        const int n3 = wn3*16 + l15;
        const short* b3p = &w3v[(size_t)n3 * H_SZ + quad*8];
        #pragma unroll
        for (int kk = 0; kk < 16; ++kk){
            bf16x8 bfrag = *(const bf16x8*)&b3p[kk*32];
            int u = kk*4 + quad;
            #pragma unroll
            for (int mf = 0; mf < 2; ++mf){
                int m = wm3*32 + mf*16 + l15;
                bf16x8 afrag = *(const bf16x8*)&Bs[m*512 + ((u ^ (m & 7))*8)];
                acc3[mf] = __builtin_amdgcn_mfma_f32_16x16x32_bf16(
                    afrag, bfrag, acc3[mf], 0, 0, 0);
            }
        }
        const int col = v*OUT_SZ + wn3*16 + l15;
        #pragma unroll
        for (int mf = 0; mf < 2; ++mf){
            int rowb = M0 + wm3*32 + mf*16 + quad*4;
            #pragma unroll
            for (int r = 0; r < 4; ++r)
                out[(size_t)(rowb + r) * (V_SZ*OUT_SZ) + col] = acc3[mf][r];
        }
    }
}

extern "C" void kernel_launch(void* const* d_in, const int* in_sizes, int n_in,
                              void* d_out, int out_size, void* d_ws, size_t ws_size,
                              hipStream_t stream)
{
    (void)in_sizes; (void)n_in; (void)out_size; (void)ws_size;
    const float* x  = (const float*)d_in[0];
    const float* W1 = (const float*)d_in[1];
    const float* b1 = (const float*)d_in[2];
    const float* W2 = (const float*)d_in[3];
    const float* b2 = (const float*)d_in[4];
    const float* W3 = (const float*)d_in[5];
    float* out = (float*)d_out;

    // workspace layout (bf16 shorts), ~288 MB — proven to fit
    char* ws = (char*)d_ws;
    short* xb  = (short*)ws;  ws += (size_t)B_SZ * IN_SZ * 2;
    short* W1t = (short*)ws;  ws += (size_t)V_SZ * H_SZ * IN_SZ * 2;      // [v][h][i]
    short* W2t = (short*)ws;  ws += (size_t)V_SZ * H_SZ * H_SZ * 2;       // [v][n][k]
    short* W3t = (short*)ws;  ws += (size_t)V_SZ * OUT_SZ * H_SZ * 2;     // [v][o][k]
    short* h1  = (short*)ws;                                              // [v][b][h]

    k_prepass<<<dim3(PRE_NBLK), dim3(256), 0, stream>>>(x, xb, W1, W1t, W2, W2t, W3, W3t);

    k_gemm1 <<<dim3(B_SZ/256, H_SZ/256, V_SZ), dim3(512), 0, stream>>>(xb, W1t, b1, h1);
    k_gemm23<<<dim3(B_SZ/64, V_SZ), dim3(512), 0, stream>>>(h1, W2t, b2, W3t, out);
}

// Round 8
// 653.280 us; speedup vs baseline: 1.0182x; 1.0182x over previous
//
#include <hip/hip_runtime.h>

#define B_SZ   4096
#define IN_SZ  1024
#define V_SZ   48
#define H_SZ   512
#define OUT_SZ 64

typedef __attribute__((ext_vector_type(4))) float f32x4;
typedef __attribute__((ext_vector_type(8))) short bf16x8;   // 8 bf16 in 4 VGPRs
typedef __attribute__((ext_vector_type(4))) short short4v;
typedef __attribute__((ext_vector_type(4))) float float4v;

// fp32 -> bf16 round-to-nearest-even
__device__ __forceinline__ short f2bf(float f){
    unsigned u = __builtin_bit_cast(unsigned, f);
    u += 0x7fffu + ((u >> 16) & 1u);
    return (short)(u >> 16);
}

// async global->LDS, 16B per lane; LDS dest is wave-uniform base + lane*16
__device__ __forceinline__ void gl2lds16(const void* g, void* l){
    __builtin_amdgcn_global_load_lds(
        (const __attribute__((address_space(1))) void*)g,
        (__attribute__((address_space(3))) void*)l, 16, 0, 0);
}

// ---------------- pre-pass: convert x to bf16 ----------------
__global__ void k_convert_x(const float* __restrict__ x, short* __restrict__ xb){
    int i = blockIdx.x * 256 + threadIdx.x;          // one float4 per thread
    float4v f = ((const float4v*)x)[i];
    short4v o = { f2bf(f.x), f2bf(f.y), f2bf(f.z), f2bf(f.w) };
    ((short4v*)xb)[i] = o;
}

// ---------------- pre-pass: out[v][c][r] = bf16(in[v][r][c]) ----------------
__global__ __launch_bounds__(256) void k_transpose_cvt4(
    const float* __restrict__ in, short* __restrict__ out, int R, int C)
{
    __shared__ short t[64][68];                      // 68-short stride: 8B-aligned rows
    int v  = blockIdx.z;
    int c0 = blockIdx.x * 64, r0 = blockIdx.y * 64;
    int tid = threadIdx.x;
    size_t base = (size_t)v * R * C;
    const float* inp = in + base + (size_t)r0 * C + c0;
    int g    = tid >> 4;                             // 0..15
    int col4 = (tid & 15) * 4;
    #pragma unroll
    for (int p = 0; p < 4; ++p){
        int row = p*16 + g;
        float4v f = *(const float4v*)&inp[(size_t)row * C + col4];
        short4v s = { f2bf(f.x), f2bf(f.y), f2bf(f.z), f2bf(f.w) };
        *(short4v*)&t[row][col4] = s;
    }
    __syncthreads();
    short* outp = out + base + (size_t)c0 * R + r0;
    int r4 = (tid & 15) * 4;
    #pragma unroll
    for (int p = 0; p < 4; ++p){
        int c = p*16 + g;
        short4v s = { t[r4+0][c], t[r4+1][c], t[r4+2][c], t[r4+3][c] };
        *(short4v*)&outp[(size_t)c * R + r4] = s;
    }
}

// ---------------- layer 1: m97-structure GEMM + bias + relu + bf16 store ----
// (proven: 278 us, 742 TF)
__global__ __launch_bounds__(256) void k_gemm1(
    const short* __restrict__ xb, const short* __restrict__ W1t,
    const float* __restrict__ b1, short* __restrict__ h1)
{
    __shared__ __align__(16) short As[128*64];
    __shared__ __align__(16) short Bs[128*64];
    const int tid  = threadIdx.x;
    const int lane = tid & 63, wave = tid >> 6;
    const int l15  = lane & 15, quad = lane >> 4;
    const int wm = wave & 1, wn = wave >> 1;
    const int M0 = blockIdx.x * 128;
    const int N0 = blockIdx.y * 128;
    const int v  = blockIdx.z;

    const short* a_base = xb  + (size_t)M0 * IN_SZ;
    const short* b_base = W1t + ((size_t)v * H_SZ + N0) * IN_SZ;

    const short* asrc[4]; const short* bsrc[4]; short* adst[4]; short* bdst[4];
    #pragma unroll
    for (int j = 0; j < 4; ++j){
        int p   = j*256 + tid;
        int row = p >> 3;
        int w   = (p & 7) ^ (row & 7);          // XOR swizzle on global side
        asrc[j] = a_base + (size_t)row * IN_SZ + w*8;
        bsrc[j] = b_base + (size_t)row * IN_SZ + w*8;
        adst[j] = &As[(size_t)(j*256 + (tid & ~63)) * 8];
        bdst[j] = &Bs[(size_t)(j*256 + (tid & ~63)) * 8];
    }

    f32x4 acc[4][4];
    #pragma unroll
    for (int i = 0; i < 4; ++i)
        #pragma unroll
        for (int j = 0; j < 4; ++j) acc[i][j] = (f32x4){0.f,0.f,0.f,0.f};

    for (int k0 = 0; k0 < IN_SZ; k0 += 64){
        #pragma unroll
        for (int j = 0; j < 4; ++j){
            gl2lds16(asrc[j] + k0, adst[j]);
            gl2lds16(bsrc[j] + k0, bdst[j]);
        }
        __syncthreads();
        #pragma unroll
        for (int kk = 0; kk < 2; ++kk){
            bf16x8 a[4], b[4];
            #pragma unroll
            for (int tm = 0; tm < 4; ++tm){
                int m = wm*64 + tm*16 + l15;
                int slot = m*8 + ((kk*4 + quad) ^ (m & 7));
                a[tm] = *(const bf16x8*)&As[slot*8];
            }
            #pragma unroll
            for (int tn = 0; tn < 4; ++tn){
                int n = wn*64 + tn*16 + l15;
                int slot = n*8 + ((kk*4 + quad) ^ (n & 7));
                b[tn] = *(const bf16x8*)&Bs[slot*8];
            }
            #pragma unroll
            for (int tm = 0; tm < 4; ++tm)
                #pragma unroll
                for (int tn = 0; tn < 4; ++tn)
                    acc[tm][tn] = __builtin_amdgcn_mfma_f32_16x16x32_bf16(
                        a[tm], b[tn], acc[tm][tn], 0, 0, 0);
        }
        __syncthreads();
    }

    const float* bv = b1 + (size_t)v * H_SZ;
    short* cv = h1 + (size_t)v * (B_SZ*H_SZ);
    #pragma unroll
    for (int tn = 0; tn < 4; ++tn){
        int col = N0 + wn*64 + tn*16 + l15;
        float bb = bv[col];
        #pragma unroll
        for (int tm = 0; tm < 4; ++tm){
            int rowb = M0 + wm*64 + tm*16 + quad*4;
            #pragma unroll
            for (int r = 0; r < 4; ++r){
                float val = acc[tm][tn][r] + bb;
                val = val > 0.f ? val : 0.f;
                cv[(size_t)(rowb + r) * H_SZ + col] = f2bf(val);
            }
        }
    }
}

// ---------------- layer 2 standalone: m97 structure, K=512 ----------------
// Clone of k_gemm1 with K=H_SZ=512 (8 k-steps), A=h1[v], B=W2t[v], bias b2,
// relu, bf16 h2 out. Moves 103 GF from the 351 TF fused BM=64 structure to
// the proven ~700 TF 128x128 structure.
__global__ __launch_bounds__(256) void k_gemm2(
    const short* __restrict__ h1, const short* __restrict__ W2t,
    const float* __restrict__ b2, short* __restrict__ h2)
{
    __shared__ __align__(16) short As[128*64];
    __shared__ __align__(16) short Bs[128*64];
    const int tid  = threadIdx.x;
    const int lane = tid & 63, wave = tid >> 6;
    const int l15  = lane & 15, quad = lane >> 4;
    const int wm = wave & 1, wn = wave >> 1;
    const int M0 = blockIdx.x * 128;
    const int N0 = blockIdx.y * 128;
    const int v  = blockIdx.z;

    const short* a_base = h1  + (size_t)v * (B_SZ*H_SZ) + (size_t)M0 * H_SZ;
    const short* b_base = W2t + ((size_t)v * H_SZ + N0) * H_SZ;

    const short* asrc[4]; const short* bsrc[4]; short* adst[4]; short* bdst[4];
    #pragma unroll
    for (int j = 0; j < 4; ++j){
        int p   = j*256 + tid;
        int row = p >> 3;
        int w   = (p & 7) ^ (row & 7);
        asrc[j] = a_base + (size_t)row * H_SZ + w*8;
        bsrc[j] = b_base + (size_t)row * H_SZ + w*8;
        adst[j] = &As[(size_t)(j*256 + (tid & ~63)) * 8];
        bdst[j] = &Bs[(size_t)(j*256 + (tid & ~63)) * 8];
    }

    f32x4 acc[4][4];
    #pragma unroll
    for (int i = 0; i < 4; ++i)
        #pragma unroll
        for (int j = 0; j < 4; ++j) acc[i][j] = (f32x4){0.f,0.f,0.f,0.f};

    for (int k0 = 0; k0 < H_SZ; k0 += 64){
        #pragma unroll
        for (int j = 0; j < 4; ++j){
            gl2lds16(asrc[j] + k0, adst[j]);
            gl2lds16(bsrc[j] + k0, bdst[j]);
        }
        __syncthreads();
        #pragma unroll
        for (int kk = 0; kk < 2; ++kk){
            bf16x8 a[4], b[4];
            #pragma unroll
            for (int tm = 0; tm < 4; ++tm){
                int m = wm*64 + tm*16 + l15;
                int slot = m*8 + ((kk*4 + quad) ^ (m & 7));
                a[tm] = *(const bf16x8*)&As[slot*8];
            }
            #pragma unroll
            for (int tn = 0; tn < 4; ++tn){
                int n = wn*64 + tn*16 + l15;
                int slot = n*8 + ((kk*4 + quad) ^ (n & 7));
                b[tn] = *(const bf16x8*)&Bs[slot*8];
            }
            #pragma unroll
            for (int tm = 0; tm < 4; ++tm)
                #pragma unroll
                for (int tn = 0; tn < 4; ++tn)
                    acc[tm][tn] = __builtin_amdgcn_mfma_f32_16x16x32_bf16(
                        a[tm], b[tn], acc[tm][tn], 0, 0, 0);
        }
        __syncthreads();
    }

    const float* bv = b2 + (size_t)v * H_SZ;
    short* cv = h2 + (size_t)v * (B_SZ*H_SZ);
    #pragma unroll
    for (int tn = 0; tn < 4; ++tn){
        int col = N0 + wn*64 + tn*16 + l15;
        float bb = bv[col];
        #pragma unroll
        for (int tm = 0; tm < 4; ++tm){
            int rowb = M0 + wm*64 + tm*16 + quad*4;
            #pragma unroll
            for (int r = 0; r < 4; ++r){
                float val = acc[tm][tn][r] + bb;
                val = val > 0.f ? val : 0.f;
                cv[(size_t)(rowb + r) * H_SZ + col] = f2bf(val);
            }
        }
    }
}

// ---------------- layer 3 standalone: BM=128, BN=64(=OUT), K=512 ----------
// 256 thr, 4 waves (2M x 2N), per-wave 64x32, acc[4][2]. 24 KB LDS.
// Memory-leaning: 201 MB h2 read + 50 MB fp32 out write. No bias, no relu.
__global__ __launch_bounds__(256) void k_gemm3(
    const short* __restrict__ h2, const short* __restrict__ W3t,
    float* __restrict__ out)
{
    __shared__ __align__(16) short As[128*64];   // 16 KB
    __shared__ __align__(16) short Bs[64*64];    // 8 KB
    const int tid  = threadIdx.x;
    const int lane = tid & 63, wave = tid >> 6;
    const int l15  = lane & 15, quad = lane >> 4;
    const int wm = wave & 1, wn = wave >> 1;     // 2M x 2N
    const int M0 = blockIdx.x * 128;
    const int v  = blockIdx.z;

    const short* a_base = h2  + (size_t)v * (B_SZ*H_SZ) + (size_t)M0 * H_SZ;
    const short* b_base = W3t + (size_t)v * (OUT_SZ*H_SZ);

    const short* asrc[4]; short* adst[4];
    #pragma unroll
    for (int j = 0; j < 4; ++j){
        int p   = j*256 + tid;
        int row = p >> 3;
        int w   = (p & 7) ^ (row & 7);
        asrc[j] = a_base + (size_t)row * H_SZ + w*8;
        adst[j] = &As[(size_t)(j*256 + (tid & ~63)) * 8];
    }
    const short* bsrc[2]; short* bdst[2];
    #pragma unroll
    for (int j = 0; j < 2; ++j){
        int p   = j*256 + tid;
        int row = p >> 3;                        // 0..63
        int w   = (p & 7) ^ (row & 7);
        bsrc[j] = b_base + (size_t)row * H_SZ + w*8;
        bdst[j] = &Bs[(size_t)(j*256 + (tid & ~63)) * 8];
    }

    f32x4 acc[4][2];
    #pragma unroll
    for (int i = 0; i < 4; ++i)
        #pragma unroll
        for (int j = 0; j < 2; ++j) acc[i][j] = (f32x4){0.f,0.f,0.f,0.f};

    for (int k0 = 0; k0 < H_SZ; k0 += 64){
        #pragma unroll
        for (int j = 0; j < 4; ++j) gl2lds16(asrc[j] + k0, adst[j]);
        #pragma unroll
        for (int j = 0; j < 2; ++j) gl2lds16(bsrc[j] + k0, bdst[j]);
        __syncthreads();
        #pragma unroll
        for (int kk = 0; kk < 2; ++kk){
            bf16x8 a[4], b[2];
            #pragma unroll
            for (int tm = 0; tm < 4; ++tm){
                int m = wm*64 + tm*16 + l15;
                int slot = m*8 + ((kk*4 + quad) ^ (m & 7));
                a[tm] = *(const bf16x8*)&As[slot*8];
            }
            #pragma unroll
            for (int tn = 0; tn < 2; ++tn){
                int n = wn*32 + tn*16 + l15;
                int slot = n*8 + ((kk*4 + quad) ^ (n & 7));
                b[tn] = *(const bf16x8*)&Bs[slot*8];
            }
            #pragma unroll
            for (int tm = 0; tm < 4; ++tm)
                #pragma unroll
                for (int tn = 0; tn < 2; ++tn)
                    acc[tm][tn] = __builtin_amdgcn_mfma_f32_16x16x32_bf16(
                        a[tm], b[tn], acc[tm][tn], 0, 0, 0);
        }
        __syncthreads();
    }

    #pragma unroll
    for (int tn = 0; tn < 2; ++tn){
        int col = v*OUT_SZ + wn*32 + tn*16 + l15;
        #pragma unroll
        for (int tm = 0; tm < 4; ++tm){
            int rowb = M0 + wm*64 + tm*16 + quad*4;
            #pragma unroll
            for (int r = 0; r < 4; ++r)
                out[(size_t)(rowb + r) * (V_SZ*OUT_SZ) + col] = acc[tm][tn][r];
        }
    }
}

// ---------------- layers 2+3 fused (FALLBACK if workspace too small) ------
__global__ __launch_bounds__(512) void k_gemm23(
    const short* __restrict__ h, const short* __restrict__ W2t,
    const float* __restrict__ b2, const short* __restrict__ W3t,
    float* __restrict__ out)
{
    __shared__ __align__(16) short As[64*64];     // 8 KB
    __shared__ __align__(16) short Bs[512*64];    // 64 KB; aliased as h2s later
    const int tid  = threadIdx.x;
    const int lane = tid & 63, wave = tid >> 6;
    const int l15  = lane & 15, quad = lane >> 4;
    const int M0 = blockIdx.x * 64;
    const int v  = blockIdx.y;

    const short* hv  = h   + (size_t)v * (B_SZ*H_SZ) + (size_t)M0 * H_SZ;
    const short* w2v = W2t + (size_t)v * (H_SZ*H_SZ);
    const short* w3v = W3t + (size_t)v * (OUT_SZ*H_SZ);

    const int rowT = tid >> 3;
    const int wT   = (tid & 7) ^ (rowT & 7);
    const short* asrc  = hv  + (size_t)rowT * H_SZ + wT*8;
    const short* bsrc0 = w2v + (size_t)rowT * H_SZ + wT*8;
    short* adst  = &As[(size_t)(tid & ~63) * 8];
    short* bdst0 = &Bs[(size_t)(tid & ~63) * 8];

    f32x4 acc[4][4];
    #pragma unroll
    for (int i = 0; i < 4; ++i)
        #pragma unroll
        for (int j = 0; j < 4; ++j) acc[i][j] = (f32x4){0.f,0.f,0.f,0.f};

    for (int k0 = 0; k0 < H_SZ; k0 += 64){
        gl2lds16(asrc + k0, adst);
        #pragma unroll
        for (int j = 0; j < 8; ++j)
            gl2lds16(bsrc0 + (size_t)j*(64*H_SZ) + k0, bdst0 + (size_t)j*512*8);
        __syncthreads();
        #pragma unroll
        for (int kk = 0; kk < 2; ++kk){
            bf16x8 a[4], b[4];
            #pragma unroll
            for (int tm = 0; tm < 4; ++tm){
                int m = tm*16 + l15;
                int slot = m*8 + ((kk*4 + quad) ^ (m & 7));
                a[tm] = *(const bf16x8*)&As[slot*8];
            }
            #pragma unroll
            for (int tn = 0; tn < 4; ++tn){
                int n = wave*64 + tn*16 + l15;
                int slot = n*8 + ((kk*4 + quad) ^ (n & 7));
                b[tn] = *(const bf16x8*)&Bs[slot*8];
            }
            #pragma unroll
            for (int tm = 0; tm < 4; ++tm)
                #pragma unroll
                for (int tn = 0; tn < 4; ++tn)
                    acc[tm][tn] = __builtin_amdgcn_mfma_f32_16x16x32_bf16(
                        a[tm], b[tn], acc[tm][tn], 0, 0, 0);
        }
        __syncthreads();
    }

    const float* bv = b2 + (size_t)v * H_SZ;
    #pragma unroll
    for (int tn = 0; tn < 4; ++tn){
        int col = wave*64 + tn*16 + l15;
        float bb = bv[col];
        int u = col >> 3, c7 = col & 7;
        #pragma unroll
        for (int tm = 0; tm < 4; ++tm){
            int rowb = tm*16 + quad*4;
            #pragma unroll
            for (int r = 0; r < 4; ++r){
                int row = rowb + r;
                float val = acc[tm][tn][r] + bb;
                val = val > 0.f ? val : 0.f;
                Bs[row*512 + ((u ^ (row & 7))*8) + c7] = f2bf(val);
            }
        }
    }
    __syncthreads();

    if (wave < 4){
        f32x4 acc3[4];
        #pragma unroll
        for (int i = 0; i < 4; ++i) acc3[i] = (f32x4){0.f,0.f,0.f,0.f};
        const int n3 = wave*16 + l15;
        const short* b3p = &w3v[(size_t)n3 * H_SZ + quad*8];
        #pragma unroll
        for (int kk = 0; kk < 16; ++kk){
            bf16x8 bfrag = *(const bf16x8*)&b3p[kk*32];
            int u = kk*4 + quad;
            #pragma unroll
            for (int tm = 0; tm < 4; ++tm){
                int m = tm*16 + l15;
                bf16x8 afrag = *(const bf16x8*)&Bs[m*512 + ((u ^ (m & 7))*8)];
                acc3[tm] = __builtin_amdgcn_mfma_f32_16x16x32_bf16(
                    afrag, bfrag, acc3[tm], 0, 0, 0);
            }
        }
        const int col = v*OUT_SZ + wave*16 + l15;
        #pragma unroll
        for (int tm = 0; tm < 4; ++tm){
            int rowb = M0 + tm*16 + quad*4;
            #pragma unroll
            for (int r = 0; r < 4; ++r)
                out[(size_t)(rowb + r) * (V_SZ*OUT_SZ) + col] = acc3[tm][r];
        }
    }
}

extern "C" void kernel_launch(void* const* d_in, const int* in_sizes, int n_in,
                              void* d_out, int out_size, void* d_ws, size_t ws_size,
                              hipStream_t stream)
{
    (void)in_sizes; (void)n_in; (void)out_size;
    const float* x  = (const float*)d_in[0];
    const float* W1 = (const float*)d_in[1];
    const float* b1 = (const float*)d_in[2];
    const float* W2 = (const float*)d_in[3];
    const float* b2 = (const float*)d_in[4];
    const float* W3 = (const float*)d_in[5];
    float* out = (float*)d_out;

    // workspace layout (bf16 shorts): base 275 MiB proven; +h2 = 467 MiB guarded
    char* ws = (char*)d_ws;
    short* xb  = (short*)ws;  ws += (size_t)B_SZ * IN_SZ * 2;
    short* W1t = (short*)ws;  ws += (size_t)V_SZ * H_SZ * IN_SZ * 2;      // [v][h][i]
    short* W2t = (short*)ws;  ws += (size_t)V_SZ * H_SZ * H_SZ * 2;       // [v][n][k]
    short* W3t = (short*)ws;  ws += (size_t)V_SZ * OUT_SZ * H_SZ * 2;     // [v][o][k]
    short* h1  = (short*)ws;  ws += (size_t)V_SZ * B_SZ * H_SZ * 2;       // [v][b][h]
    short* h2  = (short*)ws;  ws += (size_t)V_SZ * B_SZ * H_SZ * 2;       // [v][b][k]
    const size_t need_split = (size_t)(ws - (char*)d_ws);

    k_convert_x<<<dim3(B_SZ*IN_SZ/1024), dim3(256), 0, stream>>>(x, xb);
    k_transpose_cvt4<<<dim3(H_SZ/64,  IN_SZ/64, V_SZ), dim3(256), 0, stream>>>(W1, W1t, IN_SZ, H_SZ);
    k_transpose_cvt4<<<dim3(H_SZ/64,  H_SZ/64,  V_SZ), dim3(256), 0, stream>>>(W2, W2t, H_SZ, H_SZ);
    k_transpose_cvt4<<<dim3(OUT_SZ/64,H_SZ/64,  V_SZ), dim3(256), 0, stream>>>(W3, W3t, H_SZ, OUT_SZ);

    k_gemm1<<<dim3(B_SZ/128, H_SZ/128, V_SZ), dim3(256), 0, stream>>>(xb, W1t, b1, h1);

    if (ws_size >= need_split){
        // unfused path: layer 2 at m97 128x128 efficiency, then small layer-3 GEMM
        k_gemm2<<<dim3(B_SZ/128, H_SZ/128, V_SZ), dim3(256), 0, stream>>>(h1, W2t, b2, h2);
        k_gemm3<<<dim3(B_SZ/128, 1, V_SZ), dim3(256), 0, stream>>>(h2, W3t, out);
    } else {
        // fallback: proven fused kernel (R0/R6 behavior)
        k_gemm23<<<dim3(B_SZ/64, V_SZ), dim3(512), 0, stream>>>(h1, W2t, b2, W3t, out);
    }
}